// Round 2
// baseline (406.791 us; speedup 1.0000x reference)
//
#include <hip/hip_runtime.h>

// ---------------- K0: precompute Lw[o,j] = sum_k label[o,j,k] * omega[k] ----------------
__global__ void k_setup(const float* __restrict__ l1, const float* __restrict__ o1,
                        const float* __restrict__ l2, const float* __restrict__ o2,
                        const float* __restrict__ l3, const float* __restrict__ o3,
                        const float* __restrict__ lF, const float* __restrict__ oF,
                        float* __restrict__ ws) {
  int e = blockIdx.x * blockDim.x + threadIdx.x;
  if (e >= 1400) return;
  const float* lab; const float* om; float* dst; int idx;
  if (e < 400)       { lab = l1; om = o1; dst = ws;        idx = e; }
  else if (e < 800)  { lab = l2; om = o2; dst = ws + 400;  idx = e - 400; }
  else if (e < 1200) { lab = l3; om = o3; dst = ws + 800;  idx = e - 800; }
  else               { lab = lF; om = oF; dst = ws + 1200; idx = e - 1200; }
  int o = idx / 20, j = idx % 20;
  float a = 0.f;
  for (int k = 0; k < 20; ++k) a += lab[o*400 + j*20 + k] * om[k];
  dst[idx] = a;
}

// ---------------- MPS stages 1..3 ----------------
// Block = one patch p. 256 threads: b = tid&63 (batch lane), q = tid>>6 (j-quarter).
// v (length 20) propagated through S site transfer matrices:
//   M[i,j] = csum[i,j] + sum_g u_g * cdiff_g[i,j]   (phi=[u,1-u] folded)
template<int STAGE>
__global__ __launch_bounds__(256)
void k_mps(const float* __restrict__ xsrc, const float* __restrict__ ysrc,
           const float* __restrict__ cores, const float* __restrict__ alpha,
           const float* __restrict__ Lw, float* __restrict__ yout) {
  constexpr int S = (STAGE == 1) ? 3 : 20;
  __shared__ float u_lds[S][4][64];                 // [site][g][b]
  __shared__ __align__(16) float cd[400][8];        // [(i*20+j)][{cd0..cd3, csum, pad}]
  __shared__ float v_lds[64][21];                   // padded -> conflict-free

  const int p = blockIdx.x, t = threadIdx.x;
  const int b = t & 63, q = t >> 6;

  // --- gather u (the faithful raw-reshape unfold permutation) ---
  for (int k = 0; k < S; ++k) {
    float val;
    if (STAGE == 1) {
      int L = q * 3072 + p * 3 + k;           // [4,1024,3] flat
      int c = L >> 12, r = L & 4095;          // dims [3,32,32,2,2]
      int hh = 2 * (r >> 7) + ((r >> 1) & 1);
      int ww = 2 * ((r >> 2) & 31) + (r & 1);
      val = xsrc[(b * 3 + c) * 4096 + hh * 64 + ww];
    } else if (STAGE == 2) {
      int L = q * 5120 + p * 20 + k;          // [4,256,20] flat
      int c = L >> 10, r = L & 1023;          // dims [20,16,16,2,2]
      int hh = 2 * (r >> 6) + ((r >> 1) & 1);
      int ww = 2 * ((r >> 2) & 15) + (r & 1);
      val = ysrc[b * 20480 + c * 1024 + hh * 32 + ww];
    } else {
      int L = q * 1280 + p * 20 + k;          // [4,64,20] flat
      int c = L >> 8, r = L & 255;            // dims [20,8,8,2,2]
      int hh = 2 * (r >> 5) + ((r >> 1) & 1);
      int ww = 2 * ((r >> 2) & 7) + (r & 1);
      val = ysrc[b * 5120 + c * 256 + hh * 16 + ww];
    }
    u_lds[k][q][b] = val;
  }
  // v init = alpha
  for (int jj = 0; jj < 5; ++jj) v_lds[b][q * 5 + jj] = alpha[q * 5 + jj];
  __syncthreads();

  for (int s = 0; s < S; ++s) {
    // (a) build cdiff/csum for this site cooperatively
    const float* cs = cores + (size_t)(p * S + s) * 3200;
    for (int e = t; e < 400; e += 256) {
      float c0 = cs[e];
      float c1 = cs[400 + e];
      float c2 = cs[800 + e];
      float c3 = cs[1200 + e];
      float c4 = cs[1600 + e];
      float c5 = cs[2000 + e];
      float c6 = cs[2400 + e];
      float c7 = cs[2800 + e];
      float* dst = cd[e];
      dst[0] = c0 - c4; dst[1] = c1 - c5; dst[2] = c2 - c6; dst[3] = c3 - c7;
      dst[4] = c4 + c5 + c6 + c7;
    }
    __syncthreads();
    // (b) propagate v for my 5 j's
    float u0 = u_lds[s][0][b], u1 = u_lds[s][1][b];
    float u2 = u_lds[s][2][b], u3 = u_lds[s][3][b];
    float v[20];
#pragma unroll
    for (int i = 0; i < 20; ++i) v[i] = v_lds[b][i];
    float acc[5];
#pragma unroll
    for (int jj = 0; jj < 5; ++jj) {
      int j = q * 5 + jj;
      float a = 0.f;
#pragma unroll
      for (int i = 0; i < 20; ++i) {
        const float4 d4 = *(const float4*)&cd[i * 20 + j][0];  // wave-uniform broadcast
        float m = cd[i * 20 + j][4];
        m = fmaf(d4.x, u0, m);
        m = fmaf(d4.y, u1, m);
        m = fmaf(d4.z, u2, m);
        m = fmaf(d4.w, u3, m);
        a = fmaf(v[i], m, a);
      }
      acc[jj] = a;
    }
    __syncthreads();
    // (c) publish new v
#pragma unroll
    for (int jj = 0; jj < 5; ++jj) v_lds[b][q * 5 + jj] = acc[jj];
  }
  __syncthreads();

  // epilogue: y[b,p,o] = sum_j v[j] * Lw[o,j]   (layout [p][b][o] for the BN kernel)
  float vf[20];
#pragma unroll
  for (int i = 0; i < 20; ++i) vf[i] = v_lds[b][i];
#pragma unroll
  for (int jj = 0; jj < 5; ++jj) {
    int o = q * 5 + jj;
    float a = 0.f;
#pragma unroll
    for (int j = 0; j < 20; ++j) a = fmaf(vf[j], Lw[o * 20 + j], a);
    yout[p * 1280 + b * 20 + o] = a;
  }
}

// ---------------- BatchNorm1d (training mode, per-patch stats over (b,o)) ----------------
// in: y [P][64][20]; out: yn [64][P*20]  (flat layout the next stage's gather expects)
__global__ __launch_bounds__(256)
void k_bn(const float* __restrict__ y, const float* __restrict__ g,
          const float* __restrict__ bb, float* __restrict__ yn, int P) {
  const int p = blockIdx.x, t = threadIdx.x;
  __shared__ float redA[4], redB[4], stats[2];
  float vals[5];
  float s1 = 0.f, s2 = 0.f;
#pragma unroll
  for (int k = 0; k < 5; ++k) {
    float v = y[p * 1280 + k * 256 + t];
    vals[k] = v; s1 += v; s2 += v * v;
  }
#pragma unroll
  for (int o = 32; o > 0; o >>= 1) { s1 += __shfl_down(s1, o); s2 += __shfl_down(s2, o); }
  if ((t & 63) == 0) { redA[t >> 6] = s1; redB[t >> 6] = s2; }
  __syncthreads();
  if (t == 0) {
    float S1 = redA[0] + redA[1] + redA[2] + redA[3];
    float S2 = redB[0] + redB[1] + redB[2] + redB[3];
    float mu = S1 * (1.f / 1280.f);
    float var = S2 * (1.f / 1280.f) - mu * mu;
    if (var < 0.f) var = 0.f;
    stats[0] = mu; stats[1] = var;
  }
  __syncthreads();
  float mu = stats[0], var = stats[1];
  float scale = g[p] / sqrtf(var + 1e-5f);
  float shift = bb[p] - mu * scale;
#pragma unroll
  for (int k = 0; k < 5; ++k) {
    int idx = k * 256 + t;
    int bi = idx / 20, o = idx % 20;
    yn[(size_t)bi * (P * 20) + p * 20 + o] = fmaf(vals[k], scale, shift);
  }
}

// ---------------- Final MPS (S=64 sites, F=40): chunked partial matrix products ----------------
// F1: block = (b, chunk of 8 sites); builds M_s and accumulates P = M_s0 @ ... @ M_s7
__global__ __launch_bounds__(256)
void k_f1(const float* __restrict__ y3n, const float* __restrict__ coresF,
          float* __restrict__ PP) {
  const int bid = blockIdx.x;
  const int b = bid >> 3, c = bid & 7;
  const int t = threadIdx.x;
  __shared__ float ybuf[8][20];
  __shared__ float M[400];
  __shared__ float Pb[2][400];
  if (t < 160) ybuf[t / 20][t % 20] = y3n[b * 1280 + c * 160 + t];
  __syncthreads();
  int cur = 0;
  for (int s = 0; s < 8; ++s) {
    const float* cf = coresF + (size_t)(c * 8 + s) * 16000;  // [site][40][400]
    for (int e = t; e < 400; e += 256) {
      float m = 0.f;
#pragma unroll
      for (int g = 0; g < 20; ++g) {
        float lo = cf[g * 400 + e];          // phi_g = y_g
        float hi = cf[(g + 20) * 400 + e];   // phi_{g+20} = 1 - y_g
        m += fmaf(ybuf[s][g], lo - hi, hi);
      }
      M[e] = m;
    }
    __syncthreads();
    if (s == 0) {
      for (int e = t; e < 400; e += 256) Pb[0][e] = M[e];
    } else {
      for (int e = t; e < 400; e += 256) {
        int i = e / 20, j = e % 20;
        float a = 0.f;
#pragma unroll
        for (int k = 0; k < 20; ++k)
          a = fmaf(Pb[cur][i * 20 + k], M[k * 20 + j], a);
        Pb[cur ^ 1][e] = a;
      }
      cur ^= 1;
    }
    __syncthreads();
  }
  for (int e = t; e < 400; e += 256) PP[(size_t)bid * 400 + e] = Pb[cur][e];
}

// F2: combine the 8 chunk products per batch element, project to output
__global__ __launch_bounds__(256)
void k_f2(const float* __restrict__ PP, const float* __restrict__ alphaF,
          const float* __restrict__ LwF, float* __restrict__ out) {
  const int b = blockIdx.x, t = threadIdx.x;
  __shared__ float Pb[2][400];
  __shared__ float M[400];
  __shared__ float va[20];
  for (int e = t; e < 400; e += 256) Pb[0][e] = PP[(size_t)b * 3200 + e];
  int cur = 0;
  for (int c = 1; c < 8; ++c) {
    for (int e = t; e < 400; e += 256) M[e] = PP[(size_t)b * 3200 + c * 400 + e];
    __syncthreads();
    for (int e = t; e < 400; e += 256) {
      int i = e / 20, j = e % 20;
      float a = 0.f;
#pragma unroll
      for (int k = 0; k < 20; ++k) a = fmaf(Pb[cur][i * 20 + k], M[k * 20 + j], a);
      Pb[cur ^ 1][e] = a;
    }
    cur ^= 1;
    __syncthreads();
  }
  if (t < 20) {
    float a = 0.f;
#pragma unroll
    for (int i = 0; i < 20; ++i) a = fmaf(alphaF[i], Pb[cur][i * 20 + t], a);
    va[t] = a;
  }
  __syncthreads();
  if (t < 10) {
    float a = 0.f;
#pragma unroll
    for (int j = 0; j < 20; ++j) a = fmaf(va[j], LwF[t * 20 + j], a);
    out[b * 10 + t] = a;
  }
}

extern "C" void kernel_launch(void* const* d_in, const int* in_sizes, int n_in,
                              void* d_out, int out_size, void* d_ws, size_t ws_size,
                              hipStream_t stream) {
  const float* x      = (const float*)d_in[0];
  const float* cores1 = (const float*)d_in[1];
  const float* label1 = (const float*)d_in[2];
  const float* alpha1 = (const float*)d_in[3];
  const float* omega1 = (const float*)d_in[4];
  const float* g1     = (const float*)d_in[5];
  const float* b1     = (const float*)d_in[6];
  const float* cores2 = (const float*)d_in[7];
  const float* label2 = (const float*)d_in[8];
  const float* alpha2 = (const float*)d_in[9];
  const float* omega2 = (const float*)d_in[10];
  const float* g2     = (const float*)d_in[11];
  const float* b2     = (const float*)d_in[12];
  const float* cores3 = (const float*)d_in[13];
  const float* label3 = (const float*)d_in[14];
  const float* alpha3 = (const float*)d_in[15];
  const float* omega3 = (const float*)d_in[16];
  const float* g3     = (const float*)d_in[17];
  const float* b3     = (const float*)d_in[18];
  const float* coresF = (const float*)d_in[19];
  const float* labelF = (const float*)d_in[20];
  const float* alphaF = (const float*)d_in[21];
  const float* omegaF = (const float*)d_in[22];

  float* ws  = (float*)d_ws;
  float* Lw1 = ws;             // 400
  float* Lw2 = ws + 400;       // 400
  float* Lw3 = ws + 800;       // 400
  float* LwF = ws + 1200;      // 200
  // Ping-pong regions (peak ws = 1400 + 2*1310720 floats = 10.5 MB):
  float* A   = ws + 1400;      // 1310720 floats
  float* B   = A + 1310720;    // 1310720 floats
  float* y1  = A;              // 1024*64*20
  float* y1n = B;              // 64*20480
  float* y2  = A;              // 256*64*20   (y1 dead once k_mps<2> done w/ y1n... y1 consumed by k_bn1)
  float* y2n = B;              // 64*5120     (y1n consumed by k_mps<2>)
  float* y3  = A;              // 64*64*20    (y2 consumed by k_bn2)
  float* y3n = B;              // 64*1280     (y2n consumed by k_mps<3>)
  float* PP  = A;              // 512*400     (y3 consumed by k_bn3)

  float* out = (float*)d_out;

  k_setup<<<6, 256, 0, stream>>>(label1, omega1, label2, omega2,
                                 label3, omega3, labelF, omegaF, ws);
  k_mps<1><<<1024, 256, 0, stream>>>(x, nullptr, cores1, alpha1, Lw1, y1);
  k_bn<<<1024, 256, 0, stream>>>(y1, g1, b1, y1n, 1024);
  k_mps<2><<<256, 256, 0, stream>>>(nullptr, y1n, cores2, alpha2, Lw2, y2);
  k_bn<<<256, 256, 0, stream>>>(y2, g2, b2, y2n, 256);
  k_mps<3><<<64, 256, 0, stream>>>(nullptr, y2n, cores3, alpha3, Lw3, y3);
  k_bn<<<64, 256, 0, stream>>>(y3, g3, b3, y3n, 64);
  k_f1<<<512, 256, 0, stream>>>(y3n, coresF, PP);
  k_f2<<<64, 256, 0, stream>>>(PP, alphaF, LwF, out);
}

// Round 3
// 365.643 us; speedup vs baseline: 1.1125x; 1.1125x over previous
//
#include <hip/hip_runtime.h>

// ---------------- K0: precompute Lw[o,j] = sum_k label[o,j,k] * omega[k] ----------------
__global__ void k_setup(const float* __restrict__ l1, const float* __restrict__ o1,
                        const float* __restrict__ l2, const float* __restrict__ o2,
                        const float* __restrict__ l3, const float* __restrict__ o3,
                        const float* __restrict__ lF, const float* __restrict__ oF,
                        float* __restrict__ ws) {
  int e = blockIdx.x * blockDim.x + threadIdx.x;
  if (e >= 1400) return;
  const float* lab; const float* om; float* dst; int idx;
  if (e < 400)       { lab = l1; om = o1; dst = ws;        idx = e; }
  else if (e < 800)  { lab = l2; om = o2; dst = ws + 400;  idx = e - 400; }
  else if (e < 1200) { lab = l3; om = o3; dst = ws + 800;  idx = e - 800; }
  else               { lab = lF; om = oF; dst = ws + 1200; idx = e - 1200; }
  int o = idx / 20, j = idx % 20;
  float a = 0.f;
  for (int k = 0; k < 20; ++k) a += lab[o*400 + j*20 + k] * om[k];
  dst[idx] = a;
}

// ---------------- MPS stages 1..3 with fused BatchNorm ----------------
// Block = one patch p. 256 threads: b = tid&63 (batch lane, = wave lane), q = tid>>6 (wave = j-quarter).
// Software pipeline: raw cores for site s+2 load into VGPRs during compute of site s;
// cd (cdiff0..3, csum) double-buffered in LDS.
// Inter-stage layout: yn[f][b] (b innermost) -> coalesced epilogue writes & next-stage gathers.
template<int STAGE>
__global__ __launch_bounds__(256)
void k_mps(const float* __restrict__ xsrc, const float* __restrict__ ysrc,
           const float* __restrict__ cores, const float* __restrict__ alpha,
           const float* __restrict__ Lw, const float* __restrict__ gam,
           const float* __restrict__ bet, float* __restrict__ yout) {
  constexpr int S = (STAGE == 1) ? 3 : 20;
  __shared__ float u_lds[S][4][64];                 // [site][g][b]
  __shared__ __align__(16) float cd[2][400][8];     // double-buffered {cd0..3, csum, pad}
  __shared__ float v_lds[64][21];                   // pad 21 -> conflict-free scalar reads
  __shared__ float redA[4], redB[4], stats[2];

  const int p = blockIdx.x, t = threadIdx.x;
  const int b = t & 63, q = t >> 6;

  // ---- issue site-0 raw core loads early ----
  float rA[8], rB[8];
  const bool two = (t < 144);                        // 400 = 256 + 144
  {
    const float* cs = cores + (size_t)p * S * 3200;
#pragma unroll
    for (int g = 0; g < 8; ++g) rA[g] = cs[g * 400 + t];
    if (two) {
#pragma unroll
      for (int g = 0; g < 8; ++g) rB[g] = cs[g * 400 + 256 + t];
    }
  }

  // ---- gather u (faithful raw-reshape unfold permutation) ----
  for (int k = 0; k < S; ++k) {
    float val;
    if (STAGE == 1) {
      int L = q * 3072 + p * 3 + k;           // [4,1024,3] flat
      int c = L >> 12, r = L & 4095;          // dims [3,32,32,2,2]
      int hh = 2 * (r >> 7) + ((r >> 1) & 1);
      int ww = 2 * ((r >> 2) & 31) + (r & 1);
      val = xsrc[(b * 3 + c) * 4096 + hh * 64 + ww];
    } else if (STAGE == 2) {
      int L = q * 5120 + p * 20 + k;          // [4,256,20] flat
      int c = L >> 10, r = L & 1023;          // dims [20,16,16,2,2]
      int f = c * 1024 + (2 * (r >> 6) + ((r >> 1) & 1)) * 32
                        + (2 * ((r >> 2) & 15) + (r & 1));
      val = ysrc[f * 64 + b];                 // b innermost -> coalesced
    } else {
      int L = q * 1280 + p * 20 + k;          // [4,64,20] flat
      int c = L >> 8, r = L & 255;            // dims [20,8,8,2,2]
      int f = c * 256 + (2 * (r >> 5) + ((r >> 1) & 1)) * 16
                       + (2 * ((r >> 2) & 7) + (r & 1));
      val = ysrc[f * 64 + b];
    }
    u_lds[k][q][b] = val;
  }
  // v init = alpha
  for (int jj = 0; jj < 5; ++jj) v_lds[b][q * 5 + jj] = alpha[q * 5 + jj];

  // ---- build cd[0]; issue site-1 loads ----
  {
    float* d = &cd[0][t][0];
    d[0] = rA[0]-rA[4]; d[1] = rA[1]-rA[5]; d[2] = rA[2]-rA[6]; d[3] = rA[3]-rA[7];
    d[4] = rA[4]+rA[5]+rA[6]+rA[7];
    if (two) {
      float* d2 = &cd[0][t + 256][0];
      d2[0] = rB[0]-rB[4]; d2[1] = rB[1]-rB[5]; d2[2] = rB[2]-rB[6]; d2[3] = rB[3]-rB[7];
      d2[4] = rB[4]+rB[5]+rB[6]+rB[7];
    }
  }
  if (S > 1) {
    const float* cs = cores + ((size_t)p * S + 1) * 3200;
#pragma unroll
    for (int g = 0; g < 8; ++g) rA[g] = cs[g * 400 + t];
    if (two) {
#pragma unroll
      for (int g = 0; g < 8; ++g) rB[g] = cs[g * 400 + 256 + t];
    }
  }
  __syncthreads();

  for (int s = 0; s < S; ++s) {
    const int cur = s & 1;
    float u0 = u_lds[s][0][b], u1 = u_lds[s][1][b];
    float u2 = u_lds[s][2][b], u3 = u_lds[s][3][b];
    float v[20];
#pragma unroll
    for (int i = 0; i < 20; ++i) v[i] = v_lds[b][i];
    float acc[5];
#pragma unroll
    for (int jj = 0; jj < 5; ++jj) {
      int j = q * 5 + jj;
      float a = 0.f;
#pragma unroll
      for (int i = 0; i < 20; ++i) {
        const float4 d4 = *(const float4*)&cd[cur][i * 20 + j][0];  // wave-uniform broadcast
        float m = cd[cur][i * 20 + j][4];
        m = fmaf(d4.x, u0, m);
        m = fmaf(d4.y, u1, m);
        m = fmaf(d4.z, u2, m);
        m = fmaf(d4.w, u3, m);
        a = fmaf(v[i], m, a);
      }
      acc[jj] = a;
    }
    __syncthreads();
#pragma unroll
    for (int jj = 0; jj < 5; ++jj) v_lds[b][q * 5 + jj] = acc[jj];
    if (s + 1 < S) {
      // build next buffer from regs (loads issued one full site ago -> latency hidden)
      float* d = &cd[cur ^ 1][t][0];
      d[0] = rA[0]-rA[4]; d[1] = rA[1]-rA[5]; d[2] = rA[2]-rA[6]; d[3] = rA[3]-rA[7];
      d[4] = rA[4]+rA[5]+rA[6]+rA[7];
      if (two) {
        float* d2 = &cd[cur ^ 1][t + 256][0];
        d2[0] = rB[0]-rB[4]; d2[1] = rB[1]-rB[5]; d2[2] = rB[2]-rB[6]; d2[3] = rB[3]-rB[7];
        d2[4] = rB[4]+rB[5]+rB[6]+rB[7];
      }
      if (s + 2 < S) {
        const float* cs = cores + ((size_t)p * S + s + 2) * 3200;
#pragma unroll
        for (int g = 0; g < 8; ++g) rA[g] = cs[g * 400 + t];
        if (two) {
#pragma unroll
          for (int g = 0; g < 8; ++g) rB[g] = cs[g * 400 + 256 + t];
        }
      }
    }
    __syncthreads();
  }

  // ---- epilogue: Lw projection + fused BatchNorm (stats over 64b x 20o) ----
  float vf[20];
#pragma unroll
  for (int i = 0; i < 20; ++i) vf[i] = v_lds[b][i];
  float yo[5];
  float s1 = 0.f, s2 = 0.f;
#pragma unroll
  for (int jj = 0; jj < 5; ++jj) {
    int o = q * 5 + jj;
    float a = 0.f;
#pragma unroll
    for (int j = 0; j < 20; ++j) a = fmaf(vf[j], Lw[o * 20 + j], a);
    yo[jj] = a; s1 += a; s2 += a * a;
  }
#pragma unroll
  for (int off = 32; off > 0; off >>= 1) {
    s1 += __shfl_down(s1, off); s2 += __shfl_down(s2, off);
  }
  if (b == 0) { redA[q] = s1; redB[q] = s2; }
  __syncthreads();
  if (t == 0) {
    float S1 = redA[0] + redA[1] + redA[2] + redA[3];
    float S2 = redB[0] + redB[1] + redB[2] + redB[3];
    float mu = S1 * (1.f / 1280.f);
    float var = S2 * (1.f / 1280.f) - mu * mu;
    if (var < 0.f) var = 0.f;
    stats[0] = mu; stats[1] = var;
  }
  __syncthreads();
  float mu = stats[0], var = stats[1];
  float scale = gam[p] / sqrtf(var + 1e-5f);
  float shift = bet[p] - mu * scale;
#pragma unroll
  for (int jj = 0; jj < 5; ++jj) {
    int o = q * 5 + jj;
    yout[(p * 20 + o) * 64 + b] = fmaf(yo[jj], scale, shift);   // coalesced over b
  }
}

// ---------------- Final MPS (S=64 sites, F=40): chunked partial matrix products ----------------
__global__ __launch_bounds__(256)
void k_f1(const float* __restrict__ y3n, const float* __restrict__ coresF,
          float* __restrict__ PP) {
  const int bid = blockIdx.x;
  const int b = bid >> 3, c = bid & 7;
  const int t = threadIdx.x;
  __shared__ float ybuf[8][20];
  __shared__ float M[400];
  __shared__ float Pb[2][400];
  if (t < 160) ybuf[t / 20][t % 20] = y3n[(c * 160 + t) * 64 + b];
  __syncthreads();
  int cur = 0;
  for (int s = 0; s < 8; ++s) {
    const float* cf = coresF + (size_t)(c * 8 + s) * 16000;  // [site][40][400]
    for (int e = t; e < 400; e += 256) {
      float m = 0.f;
#pragma unroll
      for (int g = 0; g < 20; ++g) {
        float lo = cf[g * 400 + e];          // phi_g = y_g
        float hi = cf[(g + 20) * 400 + e];   // phi_{g+20} = 1 - y_g
        m += fmaf(ybuf[s][g], lo - hi, hi);
      }
      M[e] = m;
    }
    __syncthreads();
    if (s == 0) {
      for (int e = t; e < 400; e += 256) Pb[0][e] = M[e];
    } else {
      for (int e = t; e < 400; e += 256) {
        int i = e / 20, j = e % 20;
        float a = 0.f;
#pragma unroll
        for (int k = 0; k < 20; ++k)
          a = fmaf(Pb[cur][i * 20 + k], M[k * 20 + j], a);
        Pb[cur ^ 1][e] = a;
      }
      cur ^= 1;
    }
    __syncthreads();
  }
  for (int e = t; e < 400; e += 256) PP[(size_t)bid * 400 + e] = Pb[cur][e];
}

__global__ __launch_bounds__(256)
void k_f2(const float* __restrict__ PP, const float* __restrict__ alphaF,
          const float* __restrict__ LwF, float* __restrict__ out) {
  const int b = blockIdx.x, t = threadIdx.x;
  __shared__ float Pb[2][400];
  __shared__ float M[400];
  __shared__ float va[20];
  for (int e = t; e < 400; e += 256) Pb[0][e] = PP[(size_t)b * 3200 + e];
  int cur = 0;
  for (int c = 1; c < 8; ++c) {
    for (int e = t; e < 400; e += 256) M[e] = PP[(size_t)b * 3200 + c * 400 + e];
    __syncthreads();
    for (int e = t; e < 400; e += 256) {
      int i = e / 20, j = e % 20;
      float a = 0.f;
#pragma unroll
      for (int k = 0; k < 20; ++k) a = fmaf(Pb[cur][i * 20 + k], M[k * 20 + j], a);
      Pb[cur ^ 1][e] = a;
    }
    cur ^= 1;
    __syncthreads();
  }
  if (t < 20) {
    float a = 0.f;
#pragma unroll
    for (int i = 0; i < 20; ++i) a = fmaf(alphaF[i], Pb[cur][i * 20 + t], a);
    va[t] = a;
  }
  __syncthreads();
  if (t < 10) {
    float a = 0.f;
#pragma unroll
    for (int j = 0; j < 20; ++j) a = fmaf(va[j], LwF[t * 20 + j], a);
    out[b * 10 + t] = a;
  }
}

extern "C" void kernel_launch(void* const* d_in, const int* in_sizes, int n_in,
                              void* d_out, int out_size, void* d_ws, size_t ws_size,
                              hipStream_t stream) {
  const float* x      = (const float*)d_in[0];
  const float* cores1 = (const float*)d_in[1];
  const float* label1 = (const float*)d_in[2];
  const float* alpha1 = (const float*)d_in[3];
  const float* omega1 = (const float*)d_in[4];
  const float* g1     = (const float*)d_in[5];
  const float* b1     = (const float*)d_in[6];
  const float* cores2 = (const float*)d_in[7];
  const float* label2 = (const float*)d_in[8];
  const float* alpha2 = (const float*)d_in[9];
  const float* omega2 = (const float*)d_in[10];
  const float* g2     = (const float*)d_in[11];
  const float* b2     = (const float*)d_in[12];
  const float* cores3 = (const float*)d_in[13];
  const float* label3 = (const float*)d_in[14];
  const float* alpha3 = (const float*)d_in[15];
  const float* omega3 = (const float*)d_in[16];
  const float* g3     = (const float*)d_in[17];
  const float* b3     = (const float*)d_in[18];
  const float* coresF = (const float*)d_in[19];
  const float* labelF = (const float*)d_in[20];
  const float* alphaF = (const float*)d_in[21];
  const float* omegaF = (const float*)d_in[22];

  float* ws  = (float*)d_ws;
  float* Lw1 = ws;               // 400
  float* Lw2 = ws + 400;         // 400
  float* Lw3 = ws + 800;         // 400
  float* LwF = ws + 1200;        // 200
  float* yn1 = ws + 1400;        // 20480*64
  float* yn2 = yn1 + 1310720;    // 5120*64
  float* yn3 = yn2 + 327680;     // 1280*64
  float* PP  = yn3 + 81920;      // 512*400
  float* out = (float*)d_out;

  k_setup<<<6, 256, 0, stream>>>(label1, omega1, label2, omega2,
                                 label3, omega3, labelF, omegaF, ws);
  k_mps<1><<<1024, 256, 0, stream>>>(x, nullptr, cores1, alpha1, Lw1, g1, b1, yn1);
  k_mps<2><<<256, 256, 0, stream>>>(nullptr, yn1, cores2, alpha2, Lw2, g2, b2, yn2);
  k_mps<3><<<64, 256, 0, stream>>>(nullptr, yn2, cores3, alpha3, Lw3, g3, b3, yn3);
  k_f1<<<512, 256, 0, stream>>>(yn3, coresF, PP);
  k_f2<<<64, 256, 0, stream>>>(PP, alphaF, LwF, out);
}

// Round 4
// 256.420 us; speedup vs baseline: 1.5864x; 1.4260x over previous
//
#include <hip/hip_runtime.h>
#include <hip/hip_bf16.h>

typedef __attribute__((ext_vector_type(4))) float f32x4;
typedef __attribute__((ext_vector_type(8))) short s16x8;

static __device__ __forceinline__ short f2bf(float x) {
  __hip_bfloat16 h = __float2bfloat16(x);
  return *reinterpret_cast<short*>(&h);
}

// ---------------- K0: precompute Lw[o,j] = sum_k label[o,j,k] * omega[k] ----------------
__global__ void k_setup(const float* __restrict__ l1, const float* __restrict__ o1,
                        const float* __restrict__ l2, const float* __restrict__ o2,
                        const float* __restrict__ l3, const float* __restrict__ o3,
                        const float* __restrict__ lF, const float* __restrict__ oF,
                        float* __restrict__ ws) {
  int e = blockIdx.x * blockDim.x + threadIdx.x;
  if (e >= 1400) return;
  const float* lab; const float* om; float* dst; int idx;
  if (e < 400)       { lab = l1; om = o1; dst = ws;        idx = e; }
  else if (e < 800)  { lab = l2; om = o2; dst = ws + 400;  idx = e - 400; }
  else if (e < 1200) { lab = l3; om = o3; dst = ws + 800;  idx = e - 800; }
  else               { lab = lF; om = oF; dst = ws + 1200; idx = e - 1200; }
  int o = idx / 20, j = idx % 20;
  float a = 0.f;
  for (int k = 0; k < 20; ++k) a += lab[o*400 + j*20 + k] * om[k];
  dst[idx] = a;
}

// ---------------- MFMA MPS stages 1..3 with fused BatchNorm ----------------
// Block = patch p, 256 thr = 4 waves. Wave q owns b in [16q,16q+16).
// v (fp32, canonical in LDS) updated per site via bf16 MFMA correction:
//   dv[b][j] = sum_k W[b][k]*C'[k][j],  K = 5 blocks of 32:
//   blocks g=0..3: C'[32g+i][j]=cd_g[i][j], W=u_g*v[i]; block 4: csum-I, W=v[i].
// A-frag: A[m=lane&15][k=quad*8+j] -> lane's v-slice i=quad*8+j is static.
// B-frag: B[k=quad*8+j][n=lane&15] -> 1 ds_read_b128 per (kt,ntile).
// C/D:    col=lane&15, row=quad*4+reg.
template<int STAGE>
__global__ __launch_bounds__(256)
void k_mps(const float* __restrict__ xsrc, const float* __restrict__ ysrc,
           const float* __restrict__ cores, const float* __restrict__ alpha,
           const float* __restrict__ Lw, const float* __restrict__ gam,
           const float* __restrict__ bet, float* __restrict__ yout) {
  constexpr int S = (STAGE == 1) ? 3 : 20;
  __shared__ float u4[S][64][4];                    // [site][b][g]
  __shared__ __align__(16) short Cl[2][32][168];    // [buf][j-row][k'], pad 168 vs 160
  __shared__ __align__(16) float vls[64][36];       // [b][i], cols 20..35 zero
  __shared__ float redA[4], redB[4], stats[2];

  const int p = blockIdx.x, t = threadIdx.x;
  const int b = t & 63, q = t >> 6;
  const int m = b & 15, quad = b >> 4;
  const int bl = q * 16 + m;                         // this lane's batch row for MFMA

  // ---- issue site-0 raw core loads (in flight during init) ----
  float rA[8], rB[8];
  const bool two = (t < 144);                        // 400 = 256 + 144
  {
    const float* cs = cores + (size_t)p * S * 3200;
#pragma unroll
    for (int g = 0; g < 8; ++g) rA[g] = cs[g * 400 + t];
    if (two) {
#pragma unroll
      for (int g = 0; g < 8; ++g) rB[g] = cs[g * 400 + 256 + t];
    }
  }

  // ---- zero C', init v = alpha (cols >=20 zero) ----
  {
    int* cz = (int*)&Cl[0][0][0];                    // 2*32*168 shorts = 5376 ints
    for (int i = t; i < 5376; i += 256) cz[i] = 0;
    for (int i = t; i < 64 * 36; i += 256) {
      int col = i % 36;
      vls[i / 36][col] = (col < 20) ? alpha[col] : 0.f;
    }
  }

  // ---- gather u (faithful raw-reshape unfold permutation); u4[k][b][q] ----
  for (int k = 0; k < S; ++k) {
    float val;
    if (STAGE == 1) {
      int L = q * 3072 + p * 3 + k;           // [4,1024,3] flat
      int c = L >> 12, r = L & 4095;          // dims [3,32,32,2,2]
      int hh = 2 * (r >> 7) + ((r >> 1) & 1);
      int ww = 2 * ((r >> 2) & 31) + (r & 1);
      val = xsrc[(b * 3 + c) * 4096 + hh * 64 + ww];
    } else if (STAGE == 2) {
      int L = q * 5120 + p * 20 + k;          // [4,256,20] flat
      int c = L >> 10, r = L & 1023;          // dims [20,16,16,2,2]
      int f = c * 1024 + (2 * (r >> 6) + ((r >> 1) & 1)) * 32
                        + (2 * ((r >> 2) & 15) + (r & 1));
      val = ysrc[f * 64 + b];
    } else {
      int L = q * 1280 + p * 20 + k;          // [4,64,20] flat
      int c = L >> 8, r = L & 255;            // dims [20,8,8,2,2]
      int f = c * 256 + (2 * (r >> 5) + ((r >> 1) & 1)) * 16
                       + (2 * ((r >> 2) & 7) + (r & 1));
      val = ysrc[f * 64 + b];
    }
    u4[k][b][q] = val;
  }
  __syncthreads();   // zero-init + u visible before C' writes / reads

  // C'-entry writer: entry e=(i*20+j) from raw feature regs r[0..8]
  auto writeC = [&](int buf, int e, const float* r) {
    int i = e / 20, j = e % 20;
    Cl[buf][j][      i] = f2bf(r[0] - r[4]);
    Cl[buf][j][ 32 + i] = f2bf(r[1] - r[5]);
    Cl[buf][j][ 64 + i] = f2bf(r[2] - r[6]);
    Cl[buf][j][ 96 + i] = f2bf(r[3] - r[7]);
    float cs = r[4] + r[5] + r[6] + r[7];
    if (i == j) cs -= 1.f;
    Cl[buf][j][128 + i] = f2bf(cs);
  };

  // build C'[0]; issue site-1 loads
  writeC(0, t, rA);
  if (two) writeC(0, t + 256, rB);
  if (S > 1) {
    const float* cs = cores + ((size_t)p * S + 1) * 3200;
#pragma unroll
    for (int g = 0; g < 8; ++g) rA[g] = cs[g * 400 + t];
    if (two) {
#pragma unroll
      for (int g = 0; g < 8; ++g) rB[g] = cs[g * 400 + 256 + t];
    }
  }
  __syncthreads();

  for (int s = 0; s < S; ++s) {
    const int cur = s & 1;
    // lane state: u (4) + its v-slice (8, fp32)
    const float4 uu = *(const float4*)&u4[s][bl][0];
    const float4 va = *(const float4*)&vls[bl][quad * 8];
    const float4 vb = *(const float4*)&vls[bl][quad * 8 + 4];
    const float vv[8] = {va.x, va.y, va.z, va.w, vb.x, vb.y, vb.z, vb.w};
    const float um[5] = {uu.x, uu.y, uu.z, uu.w, 1.f};

    f32x4 acc0 = {0.f, 0.f, 0.f, 0.f};
    f32x4 acc1 = {0.f, 0.f, 0.f, 0.f};
#pragma unroll
    for (int kt = 0; kt < 5; ++kt) {
      s16x8 aF;
#pragma unroll
      for (int j2 = 0; j2 < 8; ++j2) aF[j2] = f2bf(vv[j2] * um[kt]);
      const s16x8 bF0 = *(const s16x8*)&Cl[cur][m][kt * 32 + quad * 8];
      const s16x8 bF1 = *(const s16x8*)&Cl[cur][m + 16][kt * 32 + quad * 8];
      acc0 = __builtin_amdgcn_mfma_f32_16x16x32_bf16(aF, bF0, acc0, 0, 0, 0);
      acc1 = __builtin_amdgcn_mfma_f32_16x16x32_bf16(aF, bF1, acc1, 0, 0, 0);
    }

    // stage next site's C' from regs; issue s+2 loads
    if (s + 1 < S) {
      writeC(cur ^ 1, t, rA);
      if (two) writeC(cur ^ 1, t + 256, rB);
      if (s + 2 < S) {
        const float* cs = cores + ((size_t)p * S + s + 2) * 3200;
#pragma unroll
        for (int g = 0; g < 8; ++g) rA[g] = cs[g * 400 + t];
        if (two) {
#pragma unroll
          for (int g = 0; g < 8; ++g) rB[g] = cs[g * 400 + 256 + t];
        }
      }
    }
    __syncthreads();   // all v reads done before v updates

    // v += dv  (each (b,j) owned by exactly one lane)
#pragma unroll
    for (int r = 0; r < 4; ++r) {
      const int bb = q * 16 + quad * 4 + r;
      vls[bb][m] += acc0[r];
    }
    if (m < 4) {
#pragma unroll
      for (int r = 0; r < 4; ++r) {
        const int bb = q * 16 + quad * 4 + r;
        vls[bb][m + 16] += acc1[r];
      }
    }
    __syncthreads();   // updates + next C' visible
  }

  // ---- epilogue: Lw projection + fused BatchNorm (stats over 64b x 20o) ----
  float vf[20];
  {
    const float4 v0 = *(const float4*)&vls[b][0];
    const float4 v1 = *(const float4*)&vls[b][4];
    const float4 v2 = *(const float4*)&vls[b][8];
    const float4 v3 = *(const float4*)&vls[b][12];
    const float4 v4 = *(const float4*)&vls[b][16];
    vf[0]=v0.x; vf[1]=v0.y; vf[2]=v0.z; vf[3]=v0.w;
    vf[4]=v1.x; vf[5]=v1.y; vf[6]=v1.z; vf[7]=v1.w;
    vf[8]=v2.x; vf[9]=v2.y; vf[10]=v2.z; vf[11]=v2.w;
    vf[12]=v3.x; vf[13]=v3.y; vf[14]=v3.z; vf[15]=v3.w;
    vf[16]=v4.x; vf[17]=v4.y; vf[18]=v4.z; vf[19]=v4.w;
  }
  float yo[5];
  float s1 = 0.f, s2 = 0.f;
#pragma unroll
  for (int jj = 0; jj < 5; ++jj) {
    int o = q * 5 + jj;
    float a = 0.f;
#pragma unroll
    for (int j = 0; j < 20; ++j) a = fmaf(vf[j], Lw[o * 20 + j], a);
    yo[jj] = a; s1 += a; s2 += a * a;
  }
#pragma unroll
  for (int off = 32; off > 0; off >>= 1) {
    s1 += __shfl_down(s1, off); s2 += __shfl_down(s2, off);
  }
  if (b == 0) { redA[q] = s1; redB[q] = s2; }
  __syncthreads();
  if (t == 0) {
    float S1 = redA[0] + redA[1] + redA[2] + redA[3];
    float S2 = redB[0] + redB[1] + redB[2] + redB[3];
    float mu = S1 * (1.f / 1280.f);
    float var = S2 * (1.f / 1280.f) - mu * mu;
    if (var < 0.f) var = 0.f;
    stats[0] = mu; stats[1] = var;
  }
  __syncthreads();
  float mu = stats[0], var = stats[1];
  float scale = gam[p] / sqrtf(var + 1e-5f);
  float shift = bet[p] - mu * scale;
#pragma unroll
  for (int jj = 0; jj < 5; ++jj) {
    int o = q * 5 + jj;
    yout[(p * 20 + o) * 64 + b] = fmaf(yo[jj], scale, shift);   // coalesced over b
  }
}

// ---------------- Final MPS (S=64 sites, F=40): chunked partial matrix products ----------------
__global__ __launch_bounds__(256)
void k_f1(const float* __restrict__ y3n, const float* __restrict__ coresF,
          float* __restrict__ PP) {
  const int bid = blockIdx.x;
  const int b = bid >> 3, c = bid & 7;
  const int t = threadIdx.x;
  __shared__ float ybuf[8][20];
  __shared__ float M[400];
  __shared__ float Pb[2][400];
  if (t < 160) ybuf[t / 20][t % 20] = y3n[(c * 160 + t) * 64 + b];
  __syncthreads();
  int cur = 0;
  for (int s = 0; s < 8; ++s) {
    const float* cf = coresF + (size_t)(c * 8 + s) * 16000;  // [site][40][400]
    for (int e = t; e < 400; e += 256) {
      float m = 0.f;
#pragma unroll
      for (int g = 0; g < 20; ++g) {
        float lo = cf[g * 400 + e];          // phi_g = y_g
        float hi = cf[(g + 20) * 400 + e];   // phi_{g+20} = 1 - y_g
        m += fmaf(ybuf[s][g], lo - hi, hi);
      }
      M[e] = m;
    }
    __syncthreads();
    if (s == 0) {
      for (int e = t; e < 400; e += 256) Pb[0][e] = M[e];
    } else {
      for (int e = t; e < 400; e += 256) {
        int i = e / 20, j = e % 20;
        float a = 0.f;
#pragma unroll
        for (int k = 0; k < 20; ++k)
          a = fmaf(Pb[cur][i * 20 + k], M[k * 20 + j], a);
        Pb[cur ^ 1][e] = a;
      }
      cur ^= 1;
    }
    __syncthreads();
  }
  for (int e = t; e < 400; e += 256) PP[(size_t)bid * 400 + e] = Pb[cur][e];
}

__global__ __launch_bounds__(256)
void k_f2(const float* __restrict__ PP, const float* __restrict__ alphaF,
          const float* __restrict__ LwF, float* __restrict__ out) {
  const int b = blockIdx.x, t = threadIdx.x;
  __shared__ float Pb[2][400];
  __shared__ float M[400];
  __shared__ float va[20];
  for (int e = t; e < 400; e += 256) Pb[0][e] = PP[(size_t)b * 3200 + e];
  int cur = 0;
  for (int c = 1; c < 8; ++c) {
    for (int e = t; e < 400; e += 256) M[e] = PP[(size_t)b * 3200 + c * 400 + e];
    __syncthreads();
    for (int e = t; e < 400; e += 256) {
      int i = e / 20, j = e % 20;
      float a = 0.f;
#pragma unroll
      for (int k = 0; k < 20; ++k) a = fmaf(Pb[cur][i * 20 + k], M[k * 20 + j], a);
      Pb[cur ^ 1][e] = a;
    }
    cur ^= 1;
    __syncthreads();
  }
  if (t < 20) {
    float a = 0.f;
#pragma unroll
    for (int i = 0; i < 20; ++i) a = fmaf(alphaF[i], Pb[cur][i * 20 + t], a);
    va[t] = a;
  }
  __syncthreads();
  if (t < 10) {
    float a = 0.f;
#pragma unroll
    for (int j = 0; j < 20; ++j) a = fmaf(va[j], LwF[t * 20 + j], a);
    out[b * 10 + t] = a;
  }
}

extern "C" void kernel_launch(void* const* d_in, const int* in_sizes, int n_in,
                              void* d_out, int out_size, void* d_ws, size_t ws_size,
                              hipStream_t stream) {
  const float* x      = (const float*)d_in[0];
  const float* cores1 = (const float*)d_in[1];
  const float* label1 = (const float*)d_in[2];
  const float* alpha1 = (const float*)d_in[3];
  const float* omega1 = (const float*)d_in[4];
  const float* g1     = (const float*)d_in[5];
  const float* b1     = (const float*)d_in[6];
  const float* cores2 = (const float*)d_in[7];
  const float* label2 = (const float*)d_in[8];
  const float* alpha2 = (const float*)d_in[9];
  const float* omega2 = (const float*)d_in[10];
  const float* g2     = (const float*)d_in[11];
  const float* b2     = (const float*)d_in[12];
  const float* cores3 = (const float*)d_in[13];
  const float* label3 = (const float*)d_in[14];
  const float* alpha3 = (const float*)d_in[15];
  const float* omega3 = (const float*)d_in[16];
  const float* g3     = (const float*)d_in[17];
  const float* b3     = (const float*)d_in[18];
  const float* coresF = (const float*)d_in[19];
  const float* labelF = (const float*)d_in[20];
  const float* alphaF = (const float*)d_in[21];
  const float* omegaF = (const float*)d_in[22];

  float* ws  = (float*)d_ws;
  float* Lw1 = ws;               // 400
  float* Lw2 = ws + 400;         // 400
  float* Lw3 = ws + 800;         // 400
  float* LwF = ws + 1200;        // 200
  float* yn1 = ws + 1400;        // 20480*64
  float* yn2 = yn1 + 1310720;    // 5120*64
  float* yn3 = yn2 + 327680;     // 1280*64
  float* PP  = yn3 + 81920;      // 512*400
  float* out = (float*)d_out;

  k_setup<<<6, 256, 0, stream>>>(label1, omega1, label2, omega2,
                                 label3, omega3, labelF, omegaF, ws);
  k_mps<1><<<1024, 256, 0, stream>>>(x, nullptr, cores1, alpha1, Lw1, g1, b1, yn1);
  k_mps<2><<<256, 256, 0, stream>>>(nullptr, yn1, cores2, alpha2, Lw2, g2, b2, yn2);
  k_mps<3><<<64, 256, 0, stream>>>(nullptr, yn2, cores3, alpha3, Lw3, g3, b3, yn3);
  k_f1<<<512, 256, 0, stream>>>(yn3, coresF, PP);
  k_f2<<<64, 256, 0, stream>>>(PP, alphaF, LwF, out);
}

// Round 6
// 255.661 us; speedup vs baseline: 1.5911x; 1.0030x over previous
//
#include <hip/hip_runtime.h>
#include <hip/hip_bf16.h>

typedef __attribute__((ext_vector_type(4))) float f32x4;
typedef __attribute__((ext_vector_type(8))) short s16x8;

static __device__ __forceinline__ short f2bf(float x) {
  __hip_bfloat16 h = __float2bfloat16(x);
  return *reinterpret_cast<short*>(&h);
}

// ---------------- MFMA MPS stages 1..3 with fused BatchNorm + inline Lw ----------------
// Block = patch p, 256 thr = 4 waves. Wave q owns batch rows [16q,16q+16).
// v (fp32, canonical in LDS) updated per site via bf16 MFMA correction:
//   dv[b][j] = sum_k W[b][k]*C'[k][j],  K = 5 blocks of 32:
//   blocks g=0..3: C'[32g+i][j]=cd_g[i][j], W=u_g*v[i]; block 4: csum-I, W=v[i].
// One barrier per site (v deps are intra-wave; C' double-buffer needs only the end barrier).
// Prefetch distance 3 via two ping-pong register sets (manually unrolled x2 site loop).
// NOTE: Cl must be FULLY zeroed once — writeC never touches k-columns i in 20..31 of
// rows 0..19, but B-frag reads sweep all 32 k-lanes (A is 0 there; garbage*0 can be NaN).
template<int STAGE>
__global__ __launch_bounds__(256)
void k_mps(const float* __restrict__ xsrc, const float* __restrict__ ysrc,
           const float* __restrict__ cores, const float* __restrict__ alpha,
           const float* __restrict__ label, const float* __restrict__ omega,
           const float* __restrict__ gam, const float* __restrict__ bet,
           float* __restrict__ yout) {
  constexpr int S = (STAGE == 1) ? 3 : 20;
  __shared__ __align__(16) float u4[S][64][4];      // [site][b][g]
  __shared__ __align__(16) short Cl[2][32][168];    // [buf][n-row][k'], pad 168
  __shared__ __align__(16) float vls[64][36];       // [b][i], cols 20..35 zero
  __shared__ float Lw_l[400];
  __shared__ float redA[4], redB[4], stats[2];

  const int p = blockIdx.x, t = threadIdx.x;
  const int b = t & 63, q = t >> 6;
  const int m = b & 15, quad = b >> 4;
  const int bl = q * 16 + m;

  const bool two = (t < 144);                        // 400 = 256 + 144
  const float* cbase = cores + (size_t)p * S * 3200;

  // ---- issue site-0 raw core loads (in flight during all init) ----
  float p0A[8], p0B[8], p1A[8], p1B[8];
#pragma unroll
  for (int g = 0; g < 8; ++g) p0A[g] = cbase[g * 400 + t];
  if (two) {
#pragma unroll
    for (int g = 0; g < 8; ++g) p0B[g] = cbase[g * 400 + 256 + t];
  }

  // ---- Lw[o][j] = sum_k label[o][j][k]*omega[k] (L3-hot, overlapped with prefetch) ----
  for (int e = t; e < 400; e += 256) {
    int o = e / 20, j = e % 20;
    float a = 0.f;
#pragma unroll
    for (int k = 0; k < 20; ++k) a = fmaf(label[o * 400 + j * 20 + k], omega[k], a);
    Lw_l[e] = a;
  }

  // ---- zero FULL C' (both buffers); init v = alpha (cols >=20 zero) ----
  {
    int* cz = (int*)&Cl[0][0][0];                    // 2*32*168 shorts = 5376 ints
    for (int i = t; i < 5376; i += 256) cz[i] = 0;
    for (int i = t; i < 64 * 36; i += 256) {
      int col = i % 36;
      vls[i / 36][col] = (col < 20) ? alpha[col] : 0.f;
    }
  }

  // ---- gather u (faithful raw-reshape unfold permutation); u4[k][b][g=q] ----
  for (int k = 0; k < S; ++k) {
    float val;
    if (STAGE == 1) {
      int L = q * 3072 + p * 3 + k;           // [4,1024,3] flat
      int c = L >> 12, r = L & 4095;          // dims [3,32,32,2,2]
      int hh = 2 * (r >> 7) + ((r >> 1) & 1);
      int ww = 2 * ((r >> 2) & 31) + (r & 1);
      val = xsrc[(b * 3 + c) * 4096 + hh * 64 + ww];
    } else if (STAGE == 2) {
      int L = q * 5120 + p * 20 + k;          // [4,256,20] flat
      int c = L >> 10, r = L & 1023;          // dims [20,16,16,2,2]
      int f = c * 1024 + (2 * (r >> 6) + ((r >> 1) & 1)) * 32
                        + (2 * ((r >> 2) & 15) + (r & 1));
      val = ysrc[f * 64 + b];                 // b innermost -> coalesced
    } else {
      int L = q * 1280 + p * 20 + k;          // [4,64,20] flat
      int c = L >> 8, r = L & 255;            // dims [20,8,8,2,2]
      int f = c * 256 + (2 * (r >> 5) + ((r >> 1) & 1)) * 16
                       + (2 * ((r >> 2) & 7) + (r & 1));
      val = ysrc[f * 64 + b];
    }
    u4[k][b][q] = val;
  }

  // C'-entry writer: entry e=(i*20+j) from raw feature regs r[0..8)
  auto writeC = [&](int buf, int e, const float* r) {
    int i = e / 20, j = e % 20;
    Cl[buf][j][      i] = f2bf(r[0] - r[4]);
    Cl[buf][j][ 32 + i] = f2bf(r[1] - r[5]);
    Cl[buf][j][ 64 + i] = f2bf(r[2] - r[6]);
    Cl[buf][j][ 96 + i] = f2bf(r[3] - r[7]);
    float cs = r[4] + r[5] + r[6] + r[7];
    if (i == j) cs -= 1.f;
    Cl[buf][j][128 + i] = f2bf(cs);
  };
  auto loadSite = [&](int s, float (&rA)[8], float (&rB)[8]) {
    const float* cs = cbase + (size_t)s * 3200;
#pragma unroll
    for (int g = 0; g < 8; ++g) rA[g] = cs[g * 400 + t];
    if (two) {
#pragma unroll
      for (int g = 0; g < 8; ++g) rB[g] = cs[g * 400 + 256 + t];
    }
  };

  // build C'[0] from site-0 regs; then fill the pipeline: s1 -> P0, s2 -> P1
  writeC(0, t, p0A);
  if (two) writeC(0, t + 256, p0B);
  if (S > 1) loadSite(1, p0A, p0B);
  if (S > 2) loadSite(2, p1A, p1B);
  __syncthreads();

  // ---- one site step; cur/regset passed statically (no dynamic reg indexing) ----
  auto site_step = [&](int s, int cur, float (&rA)[8], float (&rB)[8]) {
    const float4 uu = *(const float4*)&u4[s][bl][0];
    const float4 va = *(const float4*)&vls[bl][quad * 8];
    const float4 vb = *(const float4*)&vls[bl][quad * 8 + 4];
    const float vv[8] = {va.x, va.y, va.z, va.w, vb.x, vb.y, vb.z, vb.w};
    const float um[5] = {uu.x, uu.y, uu.z, uu.w, 1.f};

    f32x4 acc0 = {0.f, 0.f, 0.f, 0.f};
    f32x4 acc1 = {0.f, 0.f, 0.f, 0.f};
#pragma unroll
    for (int kt = 0; kt < 5; ++kt) {
      s16x8 aF;
#pragma unroll
      for (int j2 = 0; j2 < 8; ++j2) aF[j2] = f2bf(vv[j2] * um[kt]);
      const s16x8 bF0 = *(const s16x8*)&Cl[cur][m][kt * 32 + quad * 8];
      const s16x8 bF1 = *(const s16x8*)&Cl[cur][m + 16][kt * 32 + quad * 8];
      acc0 = __builtin_amdgcn_mfma_f32_16x16x32_bf16(aF, bF0, acc0, 0, 0, 0);
      acc1 = __builtin_amdgcn_mfma_f32_16x16x32_bf16(aF, bF1, acc1, 0, 0, 0);
    }

    // stage next site's C' (regs loaded 2 sites ago); refill this regset for s+3
    if (s + 1 < S) {
      writeC(cur ^ 1, t, rA);
      if (two) writeC(cur ^ 1, t + 256, rB);
      if (s + 3 < S) loadSite(s + 3, rA, rB);
    }

    // v += dv  (intra-wave: each (b,j) owned by exactly one lane of wave q)
#pragma unroll
    for (int r = 0; r < 4; ++r) vls[q * 16 + quad * 4 + r][m] += acc0[r];
    if (m < 4) {
#pragma unroll
      for (int r = 0; r < 4; ++r) vls[q * 16 + quad * 4 + r][m + 16] += acc1[r];
    }
    __syncthreads();   // the only per-site barrier
  };

  for (int s = 0; s < S; s += 2) {
    site_step(s, 0, p0A, p0B);
    if (s + 1 < S) site_step(s + 1, 1, p1A, p1B);
  }

  // ---- epilogue: Lw projection + fused BatchNorm (stats over 64b x 20o) ----
  float vf[20];
  {
    const float4 v0 = *(const float4*)&vls[b][0];
    const float4 v1 = *(const float4*)&vls[b][4];
    const float4 v2 = *(const float4*)&vls[b][8];
    const float4 v3 = *(const float4*)&vls[b][12];
    const float4 v4 = *(const float4*)&vls[b][16];
    vf[0]=v0.x; vf[1]=v0.y; vf[2]=v0.z; vf[3]=v0.w;
    vf[4]=v1.x; vf[5]=v1.y; vf[6]=v1.z; vf[7]=v1.w;
    vf[8]=v2.x; vf[9]=v2.y; vf[10]=v2.z; vf[11]=v2.w;
    vf[12]=v3.x; vf[13]=v3.y; vf[14]=v3.z; vf[15]=v3.w;
    vf[16]=v4.x; vf[17]=v4.y; vf[18]=v4.z; vf[19]=v4.w;
  }
  float yo[5];
  float s1 = 0.f, s2 = 0.f;
#pragma unroll
  for (int jj = 0; jj < 5; ++jj) {
    int o = q * 5 + jj;
    float a = 0.f;
#pragma unroll
    for (int j = 0; j < 20; ++j) a = fmaf(vf[j], Lw_l[o * 20 + j], a);
    yo[jj] = a; s1 += a; s2 += a * a;
  }
#pragma unroll
  for (int off = 32; off > 0; off >>= 1) {
    s1 += __shfl_down(s1, off); s2 += __shfl_down(s2, off);
  }
  if (b == 0) { redA[q] = s1; redB[q] = s2; }
  __syncthreads();
  if (t == 0) {
    float S1 = redA[0] + redA[1] + redA[2] + redA[3];
    float S2 = redB[0] + redB[1] + redB[2] + redB[3];
    float mu = S1 * (1.f / 1280.f);
    float var = S2 * (1.f / 1280.f) - mu * mu;
    if (var < 0.f) var = 0.f;
    stats[0] = mu; stats[1] = var;
  }
  __syncthreads();
  float mu = stats[0], var = stats[1];
  float scale = gam[p] / sqrtf(var + 1e-5f);
  float shift = bet[p] - mu * scale;
#pragma unroll
  for (int jj = 0; jj < 5; ++jj) {
    int o = q * 5 + jj;
    yout[(p * 20 + o) * 64 + b] = fmaf(yo[jj], scale, shift);   // coalesced over b
  }
}

// ---------------- Final MPS (S=64 sites, F=40): chunked partial matrix products ----------------
__global__ __launch_bounds__(256)
void k_f1(const float* __restrict__ y3n, const float* __restrict__ coresF,
          float* __restrict__ PP) {
  const int bid = blockIdx.x;
  const int b = bid >> 3, c = bid & 7;
  const int t = threadIdx.x;
  __shared__ float ybuf[8][20];
  __shared__ float M[400];
  __shared__ float Pb[2][400];
  if (t < 160) ybuf[t / 20][t % 20] = y3n[(c * 160 + t) * 64 + b];
  __syncthreads();
  int cur = 0;
  for (int s = 0; s < 8; ++s) {
    const float* cf = coresF + (size_t)(c * 8 + s) * 16000;  // [site][40][400]
    for (int e = t; e < 400; e += 256) {
      float m = 0.f;
#pragma unroll
      for (int g = 0; g < 20; ++g) {
        float lo = cf[g * 400 + e];          // phi_g = y_g
        float hi = cf[(g + 20) * 400 + e];   // phi_{g+20} = 1 - y_g
        m += fmaf(ybuf[s][g], lo - hi, hi);
      }
      M[e] = m;
    }
    __syncthreads();
    if (s == 0) {
      for (int e = t; e < 400; e += 256) Pb[0][e] = M[e];
    } else {
      for (int e = t; e < 400; e += 256) {
        int i = e / 20, j = e % 20;
        float a = 0.f;
#pragma unroll
        for (int k = 0; k < 20; ++k)
          a = fmaf(Pb[cur][i * 20 + k], M[k * 20 + j], a);
        Pb[cur ^ 1][e] = a;
      }
      cur ^= 1;
    }
    __syncthreads();
  }
  for (int e = t; e < 400; e += 256) PP[(size_t)bid * 400 + e] = Pb[cur][e];
}

__global__ __launch_bounds__(256)
void k_f2(const float* __restrict__ PP, const float* __restrict__ alphaF,
          const float* __restrict__ labelF, const float* __restrict__ omegaF,
          float* __restrict__ out) {
  const int b = blockIdx.x, t = threadIdx.x;
  __shared__ float Pb[2][400];
  __shared__ float M[400];
  __shared__ float va[20];
  __shared__ float LwF_l[200];
  if (t < 200) {
    int o = t / 20, j = t % 20;
    float a = 0.f;
#pragma unroll
    for (int k = 0; k < 20; ++k) a = fmaf(labelF[o * 400 + j * 20 + k], omegaF[k], a);
    LwF_l[t] = a;
  }
  for (int e = t; e < 400; e += 256) Pb[0][e] = PP[(size_t)b * 3200 + e];
  int cur = 0;
  for (int c = 1; c < 8; ++c) {
    for (int e = t; e < 400; e += 256) M[e] = PP[(size_t)b * 3200 + c * 400 + e];
    __syncthreads();
    for (int e = t; e < 400; e += 256) {
      int i = e / 20, j = e % 20;
      float a = 0.f;
#pragma unroll
      for (int k = 0; k < 20; ++k) a = fmaf(Pb[cur][i * 20 + k], M[k * 20 + j], a);
      Pb[cur ^ 1][e] = a;
    }
    cur ^= 1;
    __syncthreads();
  }
  if (t < 20) {
    float a = 0.f;
#pragma unroll
    for (int i = 0; i < 20; ++i) a = fmaf(alphaF[i], Pb[cur][i * 20 + t], a);
    va[t] = a;
  }
  __syncthreads();
  if (t < 10) {
    float a = 0.f;
#pragma unroll
    for (int j = 0; j < 20; ++j) a = fmaf(va[j], LwF_l[t * 20 + j], a);
    out[b * 10 + t] = a;
  }
}

extern "C" void kernel_launch(void* const* d_in, const int* in_sizes, int n_in,
                              void* d_out, int out_size, void* d_ws, size_t ws_size,
                              hipStream_t stream) {
  const float* x      = (const float*)d_in[0];
  const float* cores1 = (const float*)d_in[1];
  const float* label1 = (const float*)d_in[2];
  const float* alpha1 = (const float*)d_in[3];
  const float* omega1 = (const float*)d_in[4];
  const float* g1     = (const float*)d_in[5];
  const float* b1     = (const float*)d_in[6];
  const float* cores2 = (const float*)d_in[7];
  const float* label2 = (const float*)d_in[8];
  const float* alpha2 = (const float*)d_in[9];
  const float* omega2 = (const float*)d_in[10];
  const float* g2     = (const float*)d_in[11];
  const float* b2     = (const float*)d_in[12];
  const float* cores3 = (const float*)d_in[13];
  const float* label3 = (const float*)d_in[14];
  const float* alpha3 = (const float*)d_in[15];
  const float* omega3 = (const float*)d_in[16];
  const float* g3     = (const float*)d_in[17];
  const float* b3     = (const float*)d_in[18];
  const float* coresF = (const float*)d_in[19];
  const float* labelF = (const float*)d_in[20];
  const float* alphaF = (const float*)d_in[21];
  const float* omegaF = (const float*)d_in[22];

  float* ws  = (float*)d_ws;
  float* yn1 = ws;               // 20480*64
  float* yn2 = yn1 + 1310720;    // 5120*64
  float* yn3 = yn2 + 327680;     // 1280*64
  float* PP  = yn3 + 81920;      // 512*400
  float* out = (float*)d_out;

  k_mps<1><<<1024, 256, 0, stream>>>(x, nullptr, cores1, alpha1, label1, omega1, g1, b1, yn1);
  k_mps<2><<<256, 256, 0, stream>>>(nullptr, yn1, cores2, alpha2, label2, omega2, g2, b2, yn2);
  k_mps<3><<<64, 256, 0, stream>>>(nullptr, yn2, cores3, alpha3, label3, omega3, g3, b3, yn3);
  k_f1<<<512, 256, 0, stream>>>(yn3, coresF, PP);
  k_f2<<<64, 256, 0, stream>>>(PP, alphaF, labelF, omegaF, out);
}